// Round 1
// baseline (408.340 us; speedup 1.0000x reference)
//
#include <hip/hip_runtime.h>
#include <hip/hip_bf16.h>

// Stage sizes (fixed by the problem)
#define N_NODES  100000
#define E_EDGES  50000
#define U_NODES  50000
#define D        128
#define NPE      32

// ---------------------------------------------------------------------------
// GEMM: C[M,128] = A[M,128] @ W[128,128], f32.
// Block = 256 threads, 32 rows per block. W (64KB) + X tile (16KB) in LDS.
// Thread tile: 4 rows x 4 cols -> 16 fp32 acc. Safe to run in-place (C==A):
// all global reads of this block's rows complete before any write.
// ---------------------------------------------------------------------------
__global__ __launch_bounds__(256, 2) void gemm128(const float* __restrict__ A,
                                                  const float* __restrict__ W,
                                                  float* __restrict__ C, int M) {
    __shared__ float sW[128 * 128];  // 64 KB
    __shared__ float sX[32 * 128];   // 16 KB
    const int tid = threadIdx.x;

    // Stage W: 4096 float4, 16 per thread, coalesced.
    const float4* W4 = (const float4*)W;
    float4* sW4 = (float4*)sW;
#pragma unroll
    for (int i = 0; i < 16; ++i) sW4[tid + i * 256] = W4[tid + i * 256];

    const int row0 = blockIdx.x * 32;
    const int nrows = min(32, M - row0);
    const float4* A4 = (const float4*)(A + (size_t)row0 * D);
    float4* sX4 = (float4*)sX;
    for (int i = tid; i < nrows * 32; i += 256) sX4[i] = A4[i];
    __syncthreads();

    const int tx = tid & 31;   // column group: cols 4*tx .. 4*tx+3
    const int ty = tid >> 5;   // row group:    rows 4*ty .. 4*ty+3
    const int c0 = tx * 4;
    const int r0 = ty * 4;

    float acc[4][4] = {{0.f}};
#pragma unroll 8
    for (int k = 0; k < 128; ++k) {
        const float4 wv = *(const float4*)&sW[k * 128 + c0];
#pragma unroll
        for (int j = 0; j < 4; ++j) {
            const float xv = sX[(r0 + j) * 128 + k];
            acc[j][0] = fmaf(xv, wv.x, acc[j][0]);
            acc[j][1] = fmaf(xv, wv.y, acc[j][1]);
            acc[j][2] = fmaf(xv, wv.z, acc[j][2]);
            acc[j][3] = fmaf(xv, wv.w, acc[j][3]);
        }
    }

#pragma unroll
    for (int j = 0; j < 4; ++j) {
        const int r = r0 + j;
        if (r < nrows)
            *(float4*)&C[(size_t)(row0 + r) * D + c0] =
                make_float4(acc[j][0], acc[j][1], acc[j][2], acc[j][3]);
    }
}

// ---------------------------------------------------------------------------
// Gather + masked mean (+ optional relu): one wave per output row.
// weights: 1/count over slots with idx>0; if count==0, 1/32 over all slots
// (matches softmax over {1, -9e15} logits exactly, incl. underflow-to-0).
// Each lane handles 2 columns via float2 (512B/wave per gathered row).
// ---------------------------------------------------------------------------
__global__ __launch_bounds__(256) void gather_mean(const float* __restrict__ src,
                                                   const int* __restrict__ idx,
                                                   float* __restrict__ dst,
                                                   int M, int do_relu) {
    const int wid = (int)((blockIdx.x * blockDim.x + threadIdx.x) >> 6);
    if (wid >= M) return;
    const int lane = threadIdx.x & 63;

    int my = 0;
    if (lane < NPE) my = idx[(size_t)wid * NPE + lane];
    const unsigned long long b = __ballot(lane < NPE && my > 0);
    const int count = __popcll(b);
    const float scale = 1.0f / (float)(count > 0 ? count : NPE);
    const bool take_all = (count == 0);

    float ax = 0.f, ay = 0.f;
#pragma unroll 8
    for (int n = 0; n < NPE; ++n) {
        const int id = __shfl(my, n);
        if (take_all || id > 0) {
            const float2 v = ((const float2*)(src + (size_t)id * D))[lane];
            ax += v.x;
            ay += v.y;
        }
    }
    ax *= scale;
    ay *= scale;
    if (do_relu) {
        ax = fmaxf(ax, 0.f);
        ay = fmaxf(ay, 0.f);
    }
    ((float2*)(dst + (size_t)wid * D))[lane] = make_float2(ax, ay);
}

extern "C" void kernel_launch(void* const* d_in, const int* in_sizes, int n_in,
                              void* d_out, int out_size, void* d_ws, size_t ws_size,
                              hipStream_t stream) {
    const float* x  = (const float*)d_in[0];   // [N,128]
    const int*   seq = (const int*)d_in[1];    // [E,32]
    // d_in[2] text2emb: unused (dead code in reference)
    const int*   useq = (const int*)d_in[3];   // [U,32]
    // d_in[4] data_idx: unused
    const float* w1 = (const float*)d_in[5];   // [128,128]
    const float* w2 = (const float*)d_in[6];   // [128,128]
    // d_in[7] weight3: unused
    float* out = (float*)d_out;                // [U,128]

    // Workspace: h [N,128] f32 (51.2MB) | edge/e1 [E,128] f32 (25.6MB, in-place)
    float* h    = (float*)d_ws;
    float* edge = h + (size_t)N_NODES * D;

    // 1) h = x @ W1
    gemm128<<<N_NODES / 32, 256, 0, stream>>>(x, w1, h, N_NODES);

    // 2) edge = relu(masked_mean(h[seq]))
    {
        const int waves = E_EDGES;
        gather_mean<<<(waves * 64 + 255) / 256, 256, 0, stream>>>(h, seq, edge,
                                                                  E_EDGES, 1);
    }

    // 3) e1 = edge @ W2  (in-place: edge buffer overwritten)
    gemm128<<<(E_EDGES + 31) / 32, 256, 0, stream>>>(edge, w2, edge, E_EDGES);

    // 4) out = masked_mean(e1[useq])
    {
        const int waves = U_NODES;
        gather_mean<<<(waves * 64 + 255) / 256, 256, 0, stream>>>(edge, useq, out,
                                                                  U_NODES, 0);
    }
}

// Round 2
// 295.847 us; speedup vs baseline: 1.3802x; 1.3802x over previous
//
#include <hip/hip_runtime.h>
#include <hip/hip_bf16.h>

#define N_NODES  100000
#define E_EDGES  50000
#define U_NODES  50000
#define D        128
#define NPE      32

typedef __attribute__((ext_vector_type(8))) short short8;       // 8 bf16 = 4 VGPR
typedef __attribute__((ext_vector_type(4))) unsigned short u16x4;
typedef __attribute__((ext_vector_type(4))) float f32x4;

// f32 -> bf16 bits, round-to-nearest-even (finite inputs only)
static __device__ __forceinline__ unsigned short f2bf_bits(float f) {
    unsigned u = __float_as_uint(f);
    return (unsigned short)((u + 0x7fffu + ((u >> 16) & 1u)) >> 16);
}

// ---------------------------------------------------------------------------
// Prep: Wt[which][c][k] = bf16(W[k][c])  (transposed so MFMA B-fragments are
// contiguous 8-elem k-runs). 2 * 128 * 128 elements, grid 128 x 256.
// ---------------------------------------------------------------------------
__global__ void prep_wt(const float* __restrict__ w1, const float* __restrict__ w2,
                        unsigned short* __restrict__ wt) {
    const int t = blockIdx.x * 256 + threadIdx.x;   // 0..32767
    const int which = t >> 14;
    const int e = t & 16383;
    const int k = e >> 7, c = e & 127;
    const float* w = which ? w2 : w1;
    wt[which * 16384 + c * 128 + k] = f2bf_bits(w[e]);
}

// ---------------------------------------------------------------------------
// C_bf16[M,128] = A[M,128] @ W[128,128] via mfma_f32_16x16x32_bf16.
// Block: 256 thr = 4 waves, 64 rows/block; wave w owns rows 16w..16w+15,
// all 8 column-tiles (acc[8] f32x4). LDS rows padded to 136 elems ->
// fragment ds_read_b128 is 2-way-conflict (free).
// A layout (16x16x32): lane l, reg j -> A[row=l&15][k = 32*kt + 8*(l>>4)+j]
// B layout:            lane l, reg j -> W[k = 32*kt + 8*(l>>4)+j][col=l&15]
// D layout:            lane l, reg i -> D[row=4*(l>>4)+i][col=l&15]
// ---------------------------------------------------------------------------
template<int A_BF16>
__global__ __launch_bounds__(256) void gemm_mfma(const void* __restrict__ Ap,
                                                 const unsigned short* __restrict__ Wt,
                                                 unsigned short* __restrict__ C, int M) {
    __shared__ unsigned short sA[64 * 136];
    __shared__ unsigned short sW[128 * 136];
    const int tid = threadIdx.x;
    const int row0 = blockIdx.x * 64;
    const int nrows = min(64, M - row0);

    // stage Wt (bf16 [128][128]) -> sW, coalesced float4 (8 bf16)
    {
        const float4* src = (const float4*)Wt;
#pragma unroll
        for (int j = 0; j < 8; ++j) {
            const int i = tid + j * 256;            // 2048 float4
            const int r = i >> 4, c16 = i & 15;
            *(float4*)&sW[r * 136 + c16 * 8] = src[i];
        }
    }
    // stage A -> sA (convert f32->bf16 if needed); row-clamped at tail
    if (A_BF16) {
        const unsigned short* A = (const unsigned short*)Ap;
#pragma unroll
        for (int j = 0; j < 4; ++j) {
            const int i = tid + j * 256;            // 1024 float4 (8 bf16)
            const int r = i >> 4, c8 = i & 15;
            int gr = row0 + r; if (gr >= M) gr = M - 1;
            *(float4*)&sA[r * 136 + c8 * 8] = *(const float4*)&A[(size_t)gr * D + c8 * 8];
        }
    } else {
        const float* A = (const float*)Ap;
#pragma unroll
        for (int j = 0; j < 8; ++j) {
            const int i = tid + j * 256;            // 2048 float4 (4 f32)
            const int r = i >> 5, c4 = i & 31;
            int gr = row0 + r; if (gr >= M) gr = M - 1;
            const float4 v = *(const float4*)&A[(size_t)gr * D + c4 * 4];
            u16x4 p;
            p.x = f2bf_bits(v.x); p.y = f2bf_bits(v.y);
            p.z = f2bf_bits(v.z); p.w = f2bf_bits(v.w);
            *(u16x4*)&sA[r * 136 + c4 * 4] = p;
        }
    }
    __syncthreads();

    const int lane = tid & 63;
    const int wv = tid >> 6;
    const int r16 = lane & 15;
    const int hi = lane >> 4;

    short8 af[4];
#pragma unroll
    for (int kt = 0; kt < 4; ++kt)
        af[kt] = *(const short8*)&sA[(wv * 16 + r16) * 136 + kt * 32 + hi * 8];

    f32x4 acc[8];
#pragma unroll
    for (int ct = 0; ct < 8; ++ct) acc[ct] = (f32x4){0.f, 0.f, 0.f, 0.f};

#pragma unroll
    for (int ct = 0; ct < 8; ++ct) {
#pragma unroll
        for (int kt = 0; kt < 4; ++kt) {
            const short8 bf = *(const short8*)&sW[(ct * 16 + r16) * 136 + kt * 32 + hi * 8];
            acc[ct] = __builtin_amdgcn_mfma_f32_16x16x32_bf16(af[kt], bf, acc[ct], 0, 0, 0);
        }
    }

    const int lrow = wv * 16 + hi * 4;
#pragma unroll
    for (int ct = 0; ct < 8; ++ct) {
#pragma unroll
        for (int i = 0; i < 4; ++i) {
            const int r = lrow + i;
            if (r < nrows)
                C[(size_t)(row0 + r) * D + ct * 16 + r16] = f2bf_bits(acc[ct][i]);
        }
    }
}

// ---------------------------------------------------------------------------
// Gather + masked mean over bf16 rows; one wave per output row; lane reads
// one packed uint (2 bf16) per gathered row (256 B/row/wave, coalesced).
// Weights = 1/count over slots with idx>0 (all-1/32 if count==0) == softmax
// over {1, -9e15} logits exactly.
// ---------------------------------------------------------------------------
template<int OUT_BF16, int RELU>
__global__ __launch_bounds__(256) void gather_mean_bf16(
        const unsigned short* __restrict__ src, const int* __restrict__ idx,
        void* __restrict__ dst, int M) {
    const int wid = (int)((blockIdx.x * blockDim.x + threadIdx.x) >> 6);
    if (wid >= M) return;
    const int lane = threadIdx.x & 63;

    int my = 0;
    if (lane < NPE) my = idx[(size_t)wid * NPE + lane];
    const unsigned long long b = __ballot(lane < NPE && my > 0);
    const int count = __popcll(b);
    const float scale = 1.0f / (float)(count > 0 ? count : NPE);
    const bool take_all = (count == 0);

    float ax = 0.f, ay = 0.f;
#pragma unroll 8
    for (int n = 0; n < NPE; ++n) {
        const int id = __shfl(my, n);
        if (take_all || id > 0) {
            const unsigned v = ((const unsigned*)(src + (size_t)id * D))[lane];
            ax += __uint_as_float(v << 16);
            ay += __uint_as_float(v & 0xffff0000u);
        }
    }
    ax *= scale; ay *= scale;
    if (RELU) { ax = fmaxf(ax, 0.f); ay = fmaxf(ay, 0.f); }

    if (OUT_BF16) {
        const unsigned o = (unsigned)f2bf_bits(ax) | ((unsigned)f2bf_bits(ay) << 16);
        ((unsigned*)dst)[(size_t)wid * 64 + lane] = o;
    } else {
        ((float2*)dst)[(size_t)wid * 64 + lane] = make_float2(ax, ay);
    }
}

extern "C" void kernel_launch(void* const* d_in, const int* in_sizes, int n_in,
                              void* d_out, int out_size, void* d_ws, size_t ws_size,
                              hipStream_t stream) {
    const float* x   = (const float*)d_in[0];   // [N,128] f32
    const int*   seq = (const int*)d_in[1];     // [E,32]
    const int*   useq = (const int*)d_in[3];    // [U,32]
    const float* w1  = (const float*)d_in[5];   // [128,128] f32
    const float* w2  = (const float*)d_in[6];   // [128,128] f32
    float* out = (float*)d_out;                 // [U,128] f32

    // workspace: Wt (64KB) | h bf16 25.6MB | edge bf16 12.8MB | e1 bf16 12.8MB
    unsigned short* wt   = (unsigned short*)d_ws;
    unsigned short* h    = wt + 2 * 16384;
    unsigned short* edge = h + (size_t)N_NODES * D;
    unsigned short* e1   = edge + (size_t)E_EDGES * D;

    prep_wt<<<128, 256, 0, stream>>>(w1, w2, wt);

    // 1) h = bf16(x @ W1)
    gemm_mfma<0><<<(N_NODES + 63) / 64, 256, 0, stream>>>(x, wt, h, N_NODES);

    // 2) edge = bf16(relu(masked_mean(h[seq])))
    gather_mean_bf16<1, 1><<<(E_EDGES * 64 + 255) / 256, 256, 0, stream>>>(
        h, seq, edge, E_EDGES);

    // 3) e1 = bf16(edge @ W2)
    gemm_mfma<1><<<(E_EDGES + 63) / 64, 256, 0, stream>>>(edge, wt + 16384, e1, E_EDGES);

    // 4) out = masked_mean(e1[useq])  (f32 out)
    gather_mean_bf16<0, 0><<<(U_NODES * 64 + 255) / 256, 256, 0, stream>>>(
        e1, useq, out, U_NODES);
}

// Round 4
// 220.728 us; speedup vs baseline: 1.8500x; 1.3403x over previous
//
#include <hip/hip_runtime.h>
#include <hip/hip_bf16.h>

#define N_NODES  100000
#define E_EDGES  50000
#define U_NODES  50000
#define D        128
#define NPE      32

typedef __attribute__((ext_vector_type(8))) short short8;       // 8 bf16 = 4 VGPR
typedef __attribute__((ext_vector_type(4))) unsigned short u16x4;
typedef __attribute__((ext_vector_type(4))) float f32x4;

// f32 -> bf16 bits, round-to-nearest-even (finite inputs only)
static __device__ __forceinline__ unsigned short f2bf_bits(float f) {
    unsigned u = __float_as_uint(f);
    return (unsigned short)((u + 0x7fffu + ((u >> 16) & 1u)) >> 16);
}

// ---------------------------------------------------------------------------
// Prep: Wt[which][c][k] = bf16(W[k][c])  (transposed so MFMA B-fragments are
// contiguous 8-elem k-runs).
// ---------------------------------------------------------------------------
__global__ void prep_wt(const float* __restrict__ w1, const float* __restrict__ w2,
                        unsigned short* __restrict__ wt) {
    const int t = blockIdx.x * 256 + threadIdx.x;   // 0..32767
    const int which = t >> 14;
    const int e = t & 16383;
    const int k = e >> 7, c = e & 127;
    const float* w = which ? w2 : w1;
    wt[which * 16384 + c * 128 + k] = f2bf_bits(w[e]);
}

// ---------------------------------------------------------------------------
// C_bf16[M,128] = A[M,128] @ W[128,128] via mfma_f32_16x16x32_bf16.
// Grid-stride persistent blocks: W staged ONCE per block. Per 64-row tile:
// next tile's A prefetched into registers before the MFMA section; epilogue
// goes through sC (LDS) so global stores are coalesced float4.
// Frag layouts (16x16x32): A: lane l, reg j -> A[l&15][32kt + 8(l>>4)+j]
//                          B: lane l, reg j -> W[32kt + 8(l>>4)+j][l&15]
//                          D: lane l, reg i -> D[4(l>>4)+i][l&15]
// ---------------------------------------------------------------------------
template<int A_BF16>
__global__ __launch_bounds__(256) void gemm_mfma(const void* __restrict__ Ap,
                                                 const unsigned short* __restrict__ Wt,
                                                 unsigned short* __restrict__ C, int M) {
    __shared__ unsigned short sW[128 * 136];  // 34.8 KB
    __shared__ unsigned short sA[64 * 136];   // 17.4 KB
    __shared__ unsigned short sC[64 * 132];   // 16.9 KB
    const int tid = threadIdx.x;

    // stage Wt (bf16 [128][128]) -> sW once, coalesced float4 (8 bf16)
    {
        const float4* src = (const float4*)Wt;
#pragma unroll
        for (int j = 0; j < 8; ++j) {
            const int i = tid + j * 256;            // 2048 float4
            const int r = i >> 4, c16 = i & 15;
            *(float4*)&sW[r * 136 + c16 * 8] = src[i];
        }
    }

    const int ntiles = (M + 63) >> 6;
    const int lane = tid & 63;
    const int wv = tid >> 6;
    const int r16 = lane & 15;
    const int hi = lane >> 4;

    float4 pf[8];  // prefetch regs (bf16 path uses pf[0..3])

    // issue loads for a tile into pf
    auto load_tile = [&](int tile) {
        const int row0 = tile << 6;
        if (A_BF16) {
            const unsigned short* A = (const unsigned short*)Ap;
#pragma unroll
            for (int j = 0; j < 4; ++j) {
                const int i = tid + j * 256;        // 1024 x 16B (8 bf16)
                int gr = row0 + (i >> 4); if (gr >= M) gr = M - 1;
                pf[j] = *(const float4*)&A[(size_t)gr * D + (i & 15) * 8];
            }
        } else {
            const float* A = (const float*)Ap;
#pragma unroll
            for (int j = 0; j < 8; ++j) {
                const int i = tid + j * 256;        // 2048 x 16B (4 f32)
                int gr = row0 + (i >> 5); if (gr >= M) gr = M - 1;
                pf[j] = *(const float4*)&A[(size_t)gr * D + (i & 31) * 4];
            }
        }
    };
    // pf -> sA (convert if f32 path)
    auto write_tile = [&]() {
        if (A_BF16) {
#pragma unroll
            for (int j = 0; j < 4; ++j) {
                const int i = tid + j * 256;
                *(float4*)&sA[(i >> 4) * 136 + (i & 15) * 8] = pf[j];
            }
        } else {
#pragma unroll
            for (int j = 0; j < 8; ++j) {
                const int i = tid + j * 256;
                const float4 v = pf[j];
                u16x4 p;
                p.x = f2bf_bits(v.x); p.y = f2bf_bits(v.y);
                p.z = f2bf_bits(v.z); p.w = f2bf_bits(v.w);
                *(u16x4*)&sA[(i >> 5) * 136 + (i & 31) * 4] = p;
            }
        }
    };

    int tile = blockIdx.x;
    if (tile >= ntiles) return;
    load_tile(tile);

    while (tile < ntiles) {
        write_tile();
        __syncthreads();

        const int next = tile + gridDim.x;
        if (next < ntiles) load_tile(next);   // overlap HBM latency with MFMA

        short8 af[4];
#pragma unroll
        for (int kt = 0; kt < 4; ++kt)
            af[kt] = *(const short8*)&sA[(wv * 16 + r16) * 136 + kt * 32 + hi * 8];

        f32x4 acc[8];
#pragma unroll
        for (int ct = 0; ct < 8; ++ct) acc[ct] = (f32x4){0.f, 0.f, 0.f, 0.f};
#pragma unroll
        for (int ct = 0; ct < 8; ++ct) {
#pragma unroll
            for (int kt = 0; kt < 4; ++kt) {
                const short8 bf = *(const short8*)&sW[(ct * 16 + r16) * 136 + kt * 32 + hi * 8];
                acc[ct] = __builtin_amdgcn_mfma_f32_16x16x32_bf16(af[kt], bf, acc[ct], 0, 0, 0);
            }
        }
        __syncthreads();   // all sA/sW frag reads + prior sC reads complete

        // epilogue: acc -> sC (bf16), then coalesced stores
        const int row0 = tile << 6;
        const int nrows = min(64, M - row0);
#pragma unroll
        for (int ct = 0; ct < 8; ++ct)
#pragma unroll
            for (int i = 0; i < 4; ++i)
                sC[(wv * 16 + hi * 4 + i) * 132 + ct * 16 + r16] = f2bf_bits(acc[ct][i]);
        __syncthreads();
#pragma unroll
        for (int j = 0; j < 4; ++j) {
            const int i = tid + j * 256;            // 1024 x 16B chunks
            const int r = i >> 4, cc = i & 15;
            if (r < nrows)
                *(float4*)&C[(size_t)(row0 + r) * D + cc * 8] =
                    *(const float4*)&sC[r * 132 + cc * 8];
        }
        tile = next;
    }
}

// ---------------------------------------------------------------------------
// Gather + masked mean over bf16 rows; one wave per output row.
// Lane group g = lane>>4 handles slots 4i+g; each lane loads 16B (8 bf16) of
// the row -> one dwordx4 instruction covers 4 rows; 8 instructions cover all
// 32 slots and are ALL in flight before first use (v[8] = 32 VGPRs).
// Masked slots contribute via weight-0 FMA (id always in [0,N): load is safe).
// Weights = 1/count over idx>0 slots (1/32 over all if count==0) == softmax
// over {1, -9e15} exactly.
// ---------------------------------------------------------------------------
template<int OUT_BF16, int RELU>
__global__ __launch_bounds__(256) void gather_mean4(
        const unsigned short* __restrict__ src, const int* __restrict__ idx,
        void* __restrict__ dst, int M) {
    const int wid = (int)((blockIdx.x * blockDim.x + threadIdx.x) >> 6);
    if (wid >= M) return;
    const int lane = threadIdx.x & 63;
    const int g = lane >> 4;     // row-slot group
    const int c = lane & 15;     // 16B chunk within row

    int my = 0;
    if (lane < NPE) my = idx[(size_t)wid * NPE + lane];
    const unsigned long long b = __ballot(lane < NPE && my > 0);
    const int count = __popcll(b);
    const float scale = 1.0f / (float)(count > 0 ? count : NPE);
    const bool take_all = (count == 0);

    uint4 v[8];
    float w[8];
#pragma unroll
    for (int i = 0; i < 8; ++i) {
        const int id = __shfl(my, i * 4 + g);
        w[i] = (take_all || id > 0) ? scale : 0.0f;
        v[i] = *(const uint4*)(src + (size_t)id * D + c * 8);
    }

    float acc[8] = {0.f, 0.f, 0.f, 0.f, 0.f, 0.f, 0.f, 0.f};
#pragma unroll
    for (int i = 0; i < 8; ++i) {
        acc[0] = fmaf(__uint_as_float(v[i].x << 16),         w[i], acc[0]);
        acc[1] = fmaf(__uint_as_float(v[i].x & 0xffff0000u), w[i], acc[1]);
        acc[2] = fmaf(__uint_as_float(v[i].y << 16),         w[i], acc[2]);
        acc[3] = fmaf(__uint_as_float(v[i].y & 0xffff0000u), w[i], acc[3]);
        acc[4] = fmaf(__uint_as_float(v[i].z << 16),         w[i], acc[4]);
        acc[5] = fmaf(__uint_as_float(v[i].z & 0xffff0000u), w[i], acc[5]);
        acc[6] = fmaf(__uint_as_float(v[i].w << 16),         w[i], acc[6]);
        acc[7] = fmaf(__uint_as_float(v[i].w & 0xffff0000u), w[i], acc[7]);
    }

    // reduce the 4 row-groups; every lane ends with full sums for its cols
#pragma unroll
    for (int i = 0; i < 8; ++i) {
        acc[i] += __shfl_xor(acc[i], 16);
        acc[i] += __shfl_xor(acc[i], 32);
        if (RELU) acc[i] = fmaxf(acc[i], 0.f);
    }

    if (lane < 16) {
        if (OUT_BF16) {
            uint4 o;
            o.x = (unsigned)f2bf_bits(acc[0]) | ((unsigned)f2bf_bits(acc[1]) << 16);
            o.y = (unsigned)f2bf_bits(acc[2]) | ((unsigned)f2bf_bits(acc[3]) << 16);
            o.z = (unsigned)f2bf_bits(acc[4]) | ((unsigned)f2bf_bits(acc[5]) << 16);
            o.w = (unsigned)f2bf_bits(acc[6]) | ((unsigned)f2bf_bits(acc[7]) << 16);
            *(uint4*)((unsigned short*)dst + (size_t)wid * D + c * 8) = o;
        } else {
            float* dp = (float*)dst + (size_t)wid * D + c * 8;
            *(float4*)dp = make_float4(acc[0], acc[1], acc[2], acc[3]);
            *(float4*)(dp + 4) = make_float4(acc[4], acc[5], acc[6], acc[7]);
        }
    }
}

extern "C" void kernel_launch(void* const* d_in, const int* in_sizes, int n_in,
                              void* d_out, int out_size, void* d_ws, size_t ws_size,
                              hipStream_t stream) {
    const float* x    = (const float*)d_in[0];   // [N,128] f32
    const int*   seq  = (const int*)d_in[1];     // [E,32]
    const int*   useq = (const int*)d_in[3];     // [U,32]
    const float* w1   = (const float*)d_in[5];   // [128,128] f32
    const float* w2   = (const float*)d_in[6];   // [128,128] f32
    float* out = (float*)d_out;                  // [U,128] f32

    // workspace: Wt (64KB) | h bf16 25.6MB | edge bf16 12.8MB | e1 bf16 12.8MB
    unsigned short* wt   = (unsigned short*)d_ws;
    unsigned short* h    = wt + 2 * 16384;
    unsigned short* edge = h + (size_t)N_NODES * D;
    unsigned short* e1   = edge + (size_t)E_EDGES * D;

    prep_wt<<<128, 256, 0, stream>>>(w1, w2, wt);

    // 1) h = bf16(x @ W1)
    gemm_mfma<0><<<512, 256, 0, stream>>>(x, wt, h, N_NODES);

    // 2) edge = bf16(relu(masked_mean(h[seq])))
    gather_mean4<1, 1><<<(E_EDGES * 64) / 256, 256, 0, stream>>>(h, seq, edge, E_EDGES);

    // 3) e1 = bf16(edge @ W2)
    gemm_mfma<1><<<512, 256, 0, stream>>>(edge, wt + 16384, e1, E_EDGES);

    // 4) out = masked_mean(e1[useq])  (f32 out)
    gather_mean4<0, 0><<<(U_NODES * 64) / 256, 256, 0, stream>>>(e1, useq, out, U_NODES);
}